// Round 7
// baseline (793.524 us; speedup 1.0000x reference)
//
#include <hip/hip_runtime.h>
#include <hip/hip_fp16.h>

#define TT 512
#define HH 128

typedef _Float16 half4_t __attribute__((ext_vector_type(4)));
typedef _Float16 half8_t __attribute__((ext_vector_type(8)));
typedef float    float4_t __attribute__((ext_vector_type(4)));

__device__ __forceinline__ float fast_exp2(float x) {
#if __has_builtin(__builtin_amdgcn_exp2f)
    return __builtin_amdgcn_exp2f(x);
#else
    float r; asm("v_exp_f32 %0, %1" : "=v"(r) : "v"(x)); return r;
#endif
}
__device__ __forceinline__ float fast_rcp(float x) {
#if __has_builtin(__builtin_amdgcn_rcpf)
    return __builtin_amdgcn_rcpf(x);
#else
    float r; asm("v_rcp_f32 %0, %1" : "=v"(r) : "v"(x)); return r;
#endif
}
__device__ __forceinline__ float sigmoid_fast(float x) {
    return fast_rcp(1.0f + fast_exp2(-1.4426950408889634f * x));
}
__device__ __forceinline__ float tanh_fast(float x) {
    return 2.0f * fast_rcp(1.0f + fast_exp2(-2.8853900817779268f * x)) - 1.0f;
}

// LDS-only barrier: waits lgkmcnt(0), leaves global loads in flight.
__device__ __forceinline__ void wg_barrier_lds() {
#if __has_builtin(__builtin_amdgcn_s_waitcnt)
    __builtin_amdgcn_s_waitcnt(0xC07F);   // lgkmcnt(0), vmcnt=max, expcnt=max
#else
    asm volatile("s_waitcnt lgkmcnt(0)" ::: "memory");
#endif
    __builtin_amdgcn_s_barrier();
}

// ---- kernel 0: emb f32 -> f16 once (26 MB, L3-resident thereafter)
__global__ __launch_bounds__(256) void embconv_kernel(
    const float* __restrict__ emb, _Float16* __restrict__ emb16)
{
    size_t i = ((size_t)blockIdx.x * 256 + threadIdx.x) * 4;   // 12.8M elems
    float4 v = *(const float4*)(emb + i);
    half4_t h; h[0]=(_Float16)v.x; h[1]=(_Float16)v.y; h[2]=(_Float16)v.z; h[3]=(_Float16)v.w;
    *(half4_t*)(emb16 + i) = h;
}

// ---- kernel 1: fully fused BiLSTM recurrence. 16 WGs = (dir, bg), 16 chains
// each, 8 waves. Transposed MFMA (A=weights m=gate, B=activations n=chain):
// lane (lq,lm) of wave w owns (chain=lm, hdim=w*16+lq*4+r) for ALL 4 gate
// types -> all-lane acts, in-register c/h, one ds_write_b64, one lgkm-barrier
// per step. Input projection fused: 16 e-MFMAs (bias as C-input) issued before
// the h ds_read dependency; e-frags load straight from global emb16 (L1/L3).
__global__ __attribute__((amdgpu_flat_work_group_size(512, 512), amdgpu_waves_per_eu(2, 2)))
void bilstm_fused_kernel(
    const int* __restrict__ x, const _Float16* __restrict__ emb16,
    const float* __restrict__ Wih_f, const float* __restrict__ Whh_f,
    const float* __restrict__ bih_f, const float* __restrict__ bhh_f,
    const float* __restrict__ Wih_b, const float* __restrict__ Whh_b,
    const float* __restrict__ bih_b, const float* __restrict__ bhh_b,
    float* __restrict__ pooled)
{
    const int wg  = blockIdx.x;        // 0..15
    const int dir = wg >> 3, bg = wg & 7;
    const float* Wih = dir ? Wih_b : Wih_f;
    const float* Whh = dir ? Whh_b : Whh_f;
    const float* bih = dir ? bih_b : bih_f;
    const float* bhh = dir ? bhh_b : bhh_f;

    const int tid = threadIdx.x;
    const int w = tid >> 6, lane = tid & 63, lq = lane >> 4, lm = lane & 15;

    __shared__ _Float16 hsm[2][16 * 136];   // [buf][chain][hdim], +8 halfs pad

    // A-frags (m = gate row = T*128 + w*16 + lm): 128 VGPRs total
    half8_t awih[4][4], awhh[4][4];
    #pragma unroll
    for (int T = 0; T < 4; ++T) {
        #pragma unroll
        for (int kk = 0; kk < 4; ++kk) {
            const float* s1 = Wih + (size_t)(T * 128 + w * 16 + lm) * 128 + kk * 32 + lq * 8;
            const float* s2 = Whh + (size_t)(T * 128 + w * 16 + lm) * 128 + kk * 32 + lq * 8;
            half8_t a, b;
            #pragma unroll
            for (int j = 0; j < 8; ++j) { a[j] = (_Float16)s1[j]; b[j] = (_Float16)s2[j]; }
            awih[T][kk] = a; awhh[T][kk] = b;
        }
    }
    // bias as MFMA C-input: indexed by D-row = lq*4+r
    float4_t bias[4];
    #pragma unroll
    for (int T = 0; T < 4; ++T)
        #pragma unroll
        for (int r = 0; r < 4; ++r) {
            int g = T * 128 + w * 16 + lq * 4 + r;
            bias[T][r] = bih[g] + bhh[g];
        }

    for (int k = tid; k < 2 * 16 * 136; k += 512)
        ((_Float16*)hsm)[k] = (_Float16)0.0f;

    const int ch = bg * 16 + lm;           // this lane's chain
    const int* xrow = x + (size_t)ch * TT;

    // e-frag double buffer + id pipeline
    half8_t eQ[2][4];
    int ids[2];
    {
        int tl0 = dir ? (TT - 1) : 0;
        int id0 = xrow[tl0];
        #pragma unroll
        for (int kk = 0; kk < 4; ++kk)
            eQ[0][kk] = *(const half8_t*)(emb16 + (size_t)id0 * 128 + kk * 32 + lq * 8);
        int tl1 = dir ? (TT - 2) : 1;
        ids[0] = xrow[tl1];
    }
    __syncthreads();

    float c[4]    = {0.f, 0.f, 0.f, 0.f};
    float hmax[4] = {-1e30f, -1e30f, -1e30f, -1e30f};

    for (int tb = 0; tb < TT; tb += 2) {
        #pragma unroll
        for (int P = 0; P < 2; ++P) {
            const int t = tb + P;

            // prefetch e(t+1) into eQ[1-P] (addr = ids[P], loaded 2 steps ago)
            #pragma unroll
            for (int kk = 0; kk < 4; ++kk)
                eQ[1 - P][kk] = *(const half8_t*)(emb16 + (size_t)ids[P] * 128 + kk * 32 + lq * 8);
            // prefetch id(t+2) into ids[1-P]
            {
                int tl = (t + 2 < TT) ? (t + 2) : (TT - 1);
                ids[1 - P] = xrow[dir ? (TT - 1 - tl) : tl];
            }

            // input-projection MFMAs first (no h dependency; overlaps ds_read)
            float4_t acc[4];
            #pragma unroll
            for (int T = 0; T < 4; ++T)
                acc[T] = __builtin_amdgcn_mfma_f32_16x16x32_f16(awih[T][0], eQ[P][0], bias[T], 0, 0, 0);
            #pragma unroll
            for (int kk = 1; kk < 4; ++kk)
                #pragma unroll
                for (int T = 0; T < 4; ++T)
                    acc[T] = __builtin_amdgcn_mfma_f32_16x16x32_f16(awih[T][kk], eQ[P][kk], acc[T], 0, 0, 0);

            // h B-frags (n = chain = lm): 4x ds_read_b128, 2-way aliasing only
            half8_t bh[4];
            #pragma unroll
            for (int kk = 0; kk < 4; ++kk)
                bh[kk] = *(const half8_t*)&hsm[P][lm * 136 + kk * 32 + lq * 8];
            #pragma unroll
            for (int kk = 0; kk < 4; ++kk)
                #pragma unroll
                for (int T = 0; T < 4; ++T)
                    acc[T] = __builtin_amdgcn_mfma_f32_16x16x32_f16(awhh[T][kk], bh[kk], acc[T], 0, 0, 0);

            // acts: lane owns (chain=lm, hdim=w*16+lq*4+r), all 4 gate types
            half4_t hv4;
            #pragma unroll
            for (int r = 0; r < 4; ++r) {
                float ig = sigmoid_fast(acc[0][r]);
                float fg = sigmoid_fast(acc[1][r]);
                float gg = tanh_fast(acc[2][r]);
                float og = sigmoid_fast(acc[3][r]);
                c[r] = fg * c[r] + ig * gg;
                float hvf = og * tanh_fast(c[r]);
                hmax[r] = fmaxf(hmax[r], hvf);
                hv4[r] = (_Float16)hvf;
            }
            *(half4_t*)&hsm[1 - P][lm * 136 + w * 16 + lq * 4] = hv4;

            wg_barrier_lds();
        }
    }

    float4 o; o.x = hmax[0]; o.y = hmax[1]; o.z = hmax[2]; o.w = hmax[3];
    *(float4*)&pooled[(size_t)ch * 256 + dir * HH + w * 16 + lq * 4] = o;
}

// ---- kernel 2: pooled (128,256) -> relu(W1·+b1) -> sigmoid(W2·+b2) -> (128,1)
__global__ __launch_bounds__(64) void mlp_kernel(
    const float* __restrict__ pooled, const float* __restrict__ W1,
    const float* __restrict__ b1, const float* __restrict__ W2,
    const float* __restrict__ b2, float* __restrict__ out)
{
    const int b = blockIdx.x;
    const int j = threadIdx.x;
    const float4* p = (const float4*)(pooled + (size_t)b * 256);
    const float4* wv = (const float4*)(W1 + (size_t)j * 256);
    float s = 0.0f;
    #pragma unroll
    for (int q = 0; q < 64; ++q) {
        float4 pv = p[q];
        float4 ww = wv[q];
        s += pv.x * ww.x + pv.y * ww.y + pv.z * ww.z + pv.w * ww.w;
    }
    s += b1[j];
    s = fmaxf(s, 0.0f);
    float v = W2[j] * s;
    #pragma unroll
    for (int off = 32; off; off >>= 1) v += __shfl_down(v, off);
    if (j == 0) out[b] = 1.0f / (1.0f + __expf(-(v + b2[0])));
}

extern "C" void kernel_launch(void* const* d_in, const int* in_sizes, int n_in,
                              void* d_out, int out_size, void* d_ws, size_t ws_size,
                              hipStream_t stream) {
    const int*   x     = (const int*)d_in[0];
    const float* emb   = (const float*)d_in[1];
    const float* Wih_f = (const float*)d_in[2];
    const float* Whh_f = (const float*)d_in[3];
    const float* bih_f = (const float*)d_in[4];
    const float* bhh_f = (const float*)d_in[5];
    const float* Wih_b = (const float*)d_in[6];
    const float* Whh_b = (const float*)d_in[7];
    const float* bih_b = (const float*)d_in[8];
    const float* bhh_b = (const float*)d_in[9];
    const float* W1    = (const float*)d_in[10];
    const float* b1    = (const float*)d_in[11];
    const float* W2    = (const float*)d_in[12];
    const float* b2    = (const float*)d_in[13];
    float* out = (float*)d_out;

    char* ws = (char*)d_ws;
    float*    pooled = (float*)ws;                 // 128 KB
    _Float16* emb16  = (_Float16*)(ws + 131072);   // 25.6 MB (100000*128 f16)

    hipLaunchKernelGGL(embconv_kernel, dim3(12500), dim3(256), 0, stream,
                       emb, emb16);
    hipLaunchKernelGGL(bilstm_fused_kernel, dim3(16), dim3(512), 0, stream,
                       x, emb16, Wih_f, Whh_f, bih_f, bhh_f,
                       Wih_b, Whh_b, bih_b, bhh_b, pooled);
    hipLaunchKernelGGL(mlp_kernel, dim3(128), dim3(64), 0, stream,
                       pooled, W1, b1, W2, b2, out);
}

// Round 8
// 573.963 us; speedup vs baseline: 1.3825x; 1.3825x over previous
//
#include <hip/hip_runtime.h>
#include <hip/hip_fp16.h>

#define TT 512
#define HH 128

typedef _Float16 half4_t __attribute__((ext_vector_type(4)));
typedef _Float16 half8_t __attribute__((ext_vector_type(8)));
typedef float    float4_t __attribute__((ext_vector_type(4)));

__device__ __forceinline__ float fast_exp2(float x) {
#if __has_builtin(__builtin_amdgcn_exp2f)
    return __builtin_amdgcn_exp2f(x);
#else
    float r; asm("v_exp_f32 %0, %1" : "=v"(r) : "v"(x)); return r;
#endif
}
__device__ __forceinline__ float fast_rcp(float x) {
#if __has_builtin(__builtin_amdgcn_rcpf)
    return __builtin_amdgcn_rcpf(x);
#else
    float r; asm("v_rcp_f32 %0, %1" : "=v"(r) : "v"(x)); return r;
#endif
}
__device__ __forceinline__ float sigmoid_fast(float x) {
    return fast_rcp(1.0f + fast_exp2(-1.4426950408889634f * x));
}
__device__ __forceinline__ float tanh_fast(float x) {
    return 2.0f * fast_rcp(1.0f + fast_exp2(-2.8853900817779268f * x)) - 1.0f;
}

// LDS-only barrier: waits lgkmcnt(0), leaves global loads/stores in flight.
__device__ __forceinline__ void wg_barrier_lds() {
#if __has_builtin(__builtin_amdgcn_s_waitcnt)
    __builtin_amdgcn_s_waitcnt(0xC07F);   // lgkmcnt(0), vmcnt=max, expcnt=max
#else
    asm volatile("s_waitcnt lgkmcnt(0)" ::: "memory");
#endif
    __builtin_amdgcn_s_barrier();
}

// xp layout (f16): half index = (((dirbg*512 + t)*8 + w)*64 + lane)*16,
// 16 halfs per (t,w,lane) in D-order [T*4+r]. Transposed MFMA convention:
// lane (lq,lm) holds gates T*128 + w*16 + lq*4 + r for chain bg*16+lm.
__device__ __forceinline__ size_t xp_off(int dirbg, int t, int w, int lane) {
    return (((size_t)dirbg * 512 + t) * 8 + w) * 1024 + (size_t)lane * 16;
}

// ---- kernel 1: xp GEMM (transposed: A=Wih m=gate, B=emb n=chain).
// WG=(dirbg, tchunk of 32). 8 waves; bias folded as MFMA C-input. emb staged
// f32->f16 in double-buffered LDS with depth-2 global prefetch; lgkm barriers.
__global__ __attribute__((amdgpu_flat_work_group_size(512, 512), amdgpu_waves_per_eu(2, 2)))
void xp_gemm_kernel(
    const int* __restrict__ x, const float* __restrict__ emb,
    const float* __restrict__ Wih_f, const float* __restrict__ bih_f, const float* __restrict__ bhh_f,
    const float* __restrict__ Wih_b, const float* __restrict__ bih_b, const float* __restrict__ bhh_b,
    _Float16* __restrict__ xp)
{
    const int wg  = blockIdx.x;        // dirbg
    const int dir = wg >> 3, bg = wg & 7;
    const int tc  = blockIdx.y;        // t-base = tc*32

    const float* Wih = dir ? Wih_b : Wih_f;
    const float* bih = dir ? bih_b : bih_f;
    const float* bhh = dir ? bhh_b : bhh_f;

    const int tid = threadIdx.x;
    const int w = tid >> 6, lane = tid & 63, lq = lane >> 4, lm = lane & 15;

    __shared__ int id_sm[16 * 32];
    __shared__ _Float16 A[2][16 * 136];

    {   // token ids for this (chain-group, t-chunk)
        int i = tid >> 5, j = tid & 31;
        id_sm[i * 32 + j] = x[(size_t)(bg * 16 + i) * TT + tc * 32 + j];
    }

    // A-frags: m = gate = T*128 + w*16 + lm, k = kk*32 + lq*8 + j (float4 loads)
    half8_t awih[4][4];
    #pragma unroll
    for (int T = 0; T < 4; ++T) {
        #pragma unroll
        for (int kk = 0; kk < 4; ++kk) {
            const float4* s = (const float4*)(Wih + (size_t)(T * 128 + w * 16 + lm) * 128 + kk * 32 + lq * 8);
            float4 v0 = s[0], v1 = s[1];
            half8_t h;
            h[0] = (_Float16)v0.x; h[1] = (_Float16)v0.y; h[2] = (_Float16)v0.z; h[3] = (_Float16)v0.w;
            h[4] = (_Float16)v1.x; h[5] = (_Float16)v1.y; h[6] = (_Float16)v1.z; h[7] = (_Float16)v1.w;
            awih[T][kk] = h;
        }
    }
    // bias as C-input, D-row = lq*4+r (contiguous -> float4 loads)
    float4_t biasv[4];
    #pragma unroll
    for (int T = 0; T < 4; ++T) {
        int g = T * 128 + w * 16 + lq * 4;
        float4 b1 = *(const float4*)(bih + g);
        float4 b2 = *(const float4*)(bhh + g);
        biasv[T] = (float4_t){b1.x + b2.x, b1.y + b2.y, b1.z + b2.z, b1.w + b2.w};
    }
    __syncthreads();

    const int i = tid >> 5, seg = tid & 31;   // staging role: row i, float4 seg
    {   // stage t'=0
        float4 v = *(const float4*)(emb + (size_t)id_sm[i * 32] * 128 + seg * 4);
        _Float16* d = &A[0][i * 136 + seg * 4];
        d[0] = (_Float16)v.x; d[1] = (_Float16)v.y; d[2] = (_Float16)v.z; d[3] = (_Float16)v.w;
    }
    float4 eR[2];
    eR[1] = *(const float4*)(emb + (size_t)id_sm[i * 32 + 1] * 128 + seg * 4);  // e(1)
    __syncthreads();

    for (int tp = 0; tp < 32; ++tp) {
        const int buf = tp & 1;
        // issue depth-2 prefetch: e(t+2) into eR[tp&1]
        int tnx = (tp + 2 < 32) ? (tp + 2) : 31;
        float4 enew = *(const float4*)(emb + (size_t)id_sm[i * 32 + tnx] * 128 + seg * 4);

        half8_t bfr[4];
        #pragma unroll
        for (int kk = 0; kk < 4; ++kk)
            bfr[kk] = *(const half8_t*)&A[buf][lm * 136 + kk * 32 + lq * 8];

        float4_t acc[4];
        #pragma unroll
        for (int T = 0; T < 4; ++T) acc[T] = biasv[T];
        #pragma unroll
        for (int kk = 0; kk < 4; ++kk)
            #pragma unroll
            for (int T = 0; T < 4; ++T)
                acc[T] = __builtin_amdgcn_mfma_f32_16x16x32_f16(awih[T][kk], bfr[kk], acc[T], 0, 0, 0);

        half8_t p0, p1;
        #pragma unroll
        for (int r = 0; r < 4; ++r) { p0[r] = (_Float16)acc[0][r]; p0[4 + r] = (_Float16)acc[1][r]; }
        #pragma unroll
        for (int r = 0; r < 4; ++r) { p1[r] = (_Float16)acc[2][r]; p1[4 + r] = (_Float16)acc[3][r]; }
        half8_t* dst = (half8_t*)(xp + xp_off(wg, tc * 32 + tp, w, lane));
        dst[0] = p0; dst[1] = p1;

        {   // write e(t+1) (loaded last iteration) into the other buffer
            float4 v = eR[(tp + 1) & 1];
            _Float16* d = &A[1 - buf][i * 136 + seg * 4];
            d[0] = (_Float16)v.x; d[1] = (_Float16)v.y; d[2] = (_Float16)v.z; d[3] = (_Float16)v.w;
        }
        eR[buf] = enew;
        wg_barrier_lds();
    }
}

// ---- kernel 2: recurrence, transposed MFMA (A=Whh m=gate, B=h n=chain).
// 16 WGs = (dir,bg), 16 chains each, 8 waves. Lane (lq,lm) of wave w owns
// (chain=lm, hdim=w*16+lq*4+r) for ALL 4 gate types -> all-lane activations,
// in-register c/h, one ds_write_b64, one lgkm-only barrier per step. acc-init
// streams from precomputed xp (depth-2 prefetch, 4 rotating buffers).
__global__ __attribute__((amdgpu_flat_work_group_size(512, 512), amdgpu_waves_per_eu(2, 2)))
void bilstm_rec_kernel(
    const _Float16* __restrict__ xp,
    const float* __restrict__ Whh_f, const float* __restrict__ Whh_b,
    float* __restrict__ pooled)
{
    const int wg  = blockIdx.x;        // 0..15 dirbg
    const int dir = wg >> 3, bg = wg & 7;
    const float* Whh = dir ? Whh_b : Whh_f;

    const int tid = threadIdx.x;
    const int w = tid >> 6, lane = tid & 63, lq = lane >> 4, lm = lane & 15;

    __shared__ _Float16 hsm[2][16 * 136];   // [buf][chain][hdim], +8 halfs pad

    // A-frags: Whh rows (m = gate), 64 VGPRs
    half8_t awhh[4][4];
    #pragma unroll
    for (int T = 0; T < 4; ++T) {
        #pragma unroll
        for (int kk = 0; kk < 4; ++kk) {
            const float4* s = (const float4*)(Whh + (size_t)(T * 128 + w * 16 + lm) * 128 + kk * 32 + lq * 8);
            float4 v0 = s[0], v1 = s[1];
            half8_t h;
            h[0] = (_Float16)v0.x; h[1] = (_Float16)v0.y; h[2] = (_Float16)v0.z; h[3] = (_Float16)v0.w;
            h[4] = (_Float16)v1.x; h[5] = (_Float16)v1.y; h[6] = (_Float16)v1.z; h[7] = (_Float16)v1.w;
            awhh[T][kk] = h;
        }
    }

    for (int k = tid; k < 2 * 16 * 136; k += 512)
        ((_Float16*)hsm)[k] = (_Float16)0.0f;

    const _Float16* xp_wl = xp + ((size_t)wg * 512 * 8 + w) * 1024 + (size_t)lane * 16;

    // rotating 4-deep prefetch buffers, lead 2
    half8_t Qa[4], Qb[4];
    {
        int ta = dir ? (TT - 1) : 0;
        const half8_t* p = (const half8_t*)(xp_wl + (size_t)ta * 8192);
        Qa[0] = p[0]; Qb[0] = p[1];
    }
    {
        int ta = dir ? (TT - 2) : 1;
        const half8_t* p = (const half8_t*)(xp_wl + (size_t)ta * 8192);
        Qa[1] = p[0]; Qb[1] = p[1];
    }
    __syncthreads();

    float c[4]    = {0.f, 0.f, 0.f, 0.f};
    float hmax[4] = {-1e30f, -1e30f, -1e30f, -1e30f};

    for (int tb = 0; tb < TT; tb += 4) {
        #pragma unroll
        for (int P = 0; P < 4; ++P) {
            const int t = tb + P;
            {   // prefetch xp(t+2) into buffer (P+2)&3
                int tl = (t + 2 < TT) ? (t + 2) : (TT - 1);
                int ta = dir ? (TT - 1 - tl) : tl;
                const half8_t* pp = (const half8_t*)(xp_wl + (size_t)ta * 8192);
                Qa[(P + 2) & 3] = pp[0]; Qb[(P + 2) & 3] = pp[1];
            }

            // h B-frags (n = chain = lm)
            half8_t bh[4];
            #pragma unroll
            for (int kk = 0; kk < 4; ++kk)
                bh[kk] = *(const half8_t*)&hsm[P & 1][lm * 136 + kk * 32 + lq * 8];

            // acc init from xp (bias pre-folded): D-order [T*4+r]
            float4_t acc[4];
            acc[0] = (float4_t){(float)Qa[P][0], (float)Qa[P][1], (float)Qa[P][2], (float)Qa[P][3]};
            acc[1] = (float4_t){(float)Qa[P][4], (float)Qa[P][5], (float)Qa[P][6], (float)Qa[P][7]};
            acc[2] = (float4_t){(float)Qb[P][0], (float)Qb[P][1], (float)Qb[P][2], (float)Qb[P][3]};
            acc[3] = (float4_t){(float)Qb[P][4], (float)Qb[P][5], (float)Qb[P][6], (float)Qb[P][7]};
            #pragma unroll
            for (int kk = 0; kk < 4; ++kk)
                #pragma unroll
                for (int T = 0; T < 4; ++T)
                    acc[T] = __builtin_amdgcn_mfma_f32_16x16x32_f16(awhh[T][kk], bh[kk], acc[T], 0, 0, 0);

            // acts: lane owns (chain=lm, hdim=w*16+lq*4+r), all 4 gate types
            half4_t hv4;
            #pragma unroll
            for (int r = 0; r < 4; ++r) {
                float ig = sigmoid_fast(acc[0][r]);
                float fg = sigmoid_fast(acc[1][r]);
                float gg = tanh_fast(acc[2][r]);
                float og = sigmoid_fast(acc[3][r]);
                c[r] = fg * c[r] + ig * gg;
                float hvf = og * tanh_fast(c[r]);
                hmax[r] = fmaxf(hmax[r], hvf);
                hv4[r] = (_Float16)hvf;
            }
            *(half4_t*)&hsm[1 - (P & 1)][lm * 136 + w * 16 + lq * 4] = hv4;

            wg_barrier_lds();
        }
    }

    float4 o; o.x = hmax[0]; o.y = hmax[1]; o.z = hmax[2]; o.w = hmax[3];
    *(float4*)&pooled[(size_t)(bg * 16 + lm) * 256 + dir * HH + w * 16 + lq * 4] = o;
}

// ---- kernel 3: pooled (128,256) -> relu(W1·+b1) -> sigmoid(W2·+b2) -> (128,1)
__global__ __launch_bounds__(64) void mlp_kernel(
    const float* __restrict__ pooled, const float* __restrict__ W1,
    const float* __restrict__ b1, const float* __restrict__ W2,
    const float* __restrict__ b2, float* __restrict__ out)
{
    const int b = blockIdx.x;
    const int j = threadIdx.x;
    const float4* p = (const float4*)(pooled + (size_t)b * 256);
    const float4* wv = (const float4*)(W1 + (size_t)j * 256);
    float s = 0.0f;
    #pragma unroll
    for (int q = 0; q < 64; ++q) {
        float4 pv = p[q];
        float4 ww = wv[q];
        s += pv.x * ww.x + pv.y * ww.y + pv.z * ww.z + pv.w * ww.w;
    }
    s += b1[j];
    s = fmaxf(s, 0.0f);
    float v = W2[j] * s;
    #pragma unroll
    for (int off = 32; off; off >>= 1) v += __shfl_down(v, off);
    if (j == 0) out[b] = 1.0f / (1.0f + __expf(-(v + b2[0])));
}

extern "C" void kernel_launch(void* const* d_in, const int* in_sizes, int n_in,
                              void* d_out, int out_size, void* d_ws, size_t ws_size,
                              hipStream_t stream) {
    const int*   x     = (const int*)d_in[0];
    const float* emb   = (const float*)d_in[1];
    const float* Wih_f = (const float*)d_in[2];
    const float* Whh_f = (const float*)d_in[3];
    const float* bih_f = (const float*)d_in[4];
    const float* bhh_f = (const float*)d_in[5];
    const float* Wih_b = (const float*)d_in[6];
    const float* Whh_b = (const float*)d_in[7];
    const float* bih_b = (const float*)d_in[8];
    const float* bhh_b = (const float*)d_in[9];
    const float* W1    = (const float*)d_in[10];
    const float* b1    = (const float*)d_in[11];
    const float* W2    = (const float*)d_in[12];
    const float* b2    = (const float*)d_in[13];
    float* out = (float*)d_out;

    char* ws = (char*)d_ws;
    float*    pooled = (float*)ws;                 // 128 KB
    _Float16* xp     = (_Float16*)(ws + 131072);   // 134.2 MB

    hipLaunchKernelGGL(xp_gemm_kernel, dim3(16, 16), dim3(512), 0, stream,
                       x, emb, Wih_f, bih_f, bhh_f, Wih_b, bih_b, bhh_b, xp);
    hipLaunchKernelGGL(bilstm_rec_kernel, dim3(16), dim3(512), 0, stream,
                       xp, Whh_f, Whh_b, pooled);
    hipLaunchKernelGGL(mlp_kernel, dim3(128), dim3(64), 0, stream,
                       pooled, W1, b1, W2, b2, out);
}

// Round 10
// 533.946 us; speedup vs baseline: 1.4862x; 1.0749x over previous
//
#include <hip/hip_runtime.h>
#include <hip/hip_fp16.h>

#define TT 512
#define HH 128

typedef _Float16 half2_t __attribute__((ext_vector_type(2)));
typedef _Float16 half4_t __attribute__((ext_vector_type(4)));
typedef _Float16 half8_t __attribute__((ext_vector_type(8)));
typedef float    float4_t __attribute__((ext_vector_type(4)));

__device__ __forceinline__ half2_t h2(float v) {
    half2_t r; r[0] = (_Float16)v; r[1] = (_Float16)v; return r;
}
__device__ __forceinline__ half2_t pkrtz(float a, float b) {
    return __builtin_bit_cast(half2_t, __builtin_amdgcn_cvt_pkrtz(a, b));
}

// ---- packed-f16 polynomial activations (no transcendentals) ----
// tanh(x) ~= x*(C1 + C3 t + C5 t^2 + C7 t^3), t=x^2, |x|<=2 (clamped), err<=4e-3
// sigma(x) = 0.5 + 0.5*tanh(x/2) -> 0.5 + x*(S1 + S3 t + S5 t^2 + S7 t^3), |x|<=4
#define TC1 0.994940f
#define TC3 -0.290799f
#define TC5 0.065507f
#define TC7 -0.0062464f
#define SC1 0.2487350f
#define SC3 -0.0181749f
#define SC5 0.00102355f
#define SC7 -0.0000244141f

__device__ __forceinline__ half2_t tanh_pk(half2_t x) {
    half2_t m = __builtin_elementwise_min(__builtin_elementwise_max(x, h2(-2.0f)), h2(2.0f));
    half2_t t = m * m;
    half2_t p = h2(TC7) * t + h2(TC5);
    p = p * t + h2(TC3);
    p = p * t + h2(TC1);
    return m * p;
}
__device__ __forceinline__ half2_t sigma_pk(half2_t x) {
    half2_t m = __builtin_elementwise_min(__builtin_elementwise_max(x, h2(-4.0f)), h2(4.0f));
    half2_t t = m * m;
    half2_t p = h2(SC7) * t + h2(SC5);
    p = p * t + h2(SC3);
    p = p * t + h2(SC1);
    return m * p + h2(0.5f);
}

// LDS-only barrier: waits lgkmcnt(0), leaves global loads/stores in flight.
__device__ __forceinline__ void wg_barrier_lds() {
#if __has_builtin(__builtin_amdgcn_s_waitcnt)
    __builtin_amdgcn_s_waitcnt(0xC07F);   // lgkmcnt(0), vmcnt=max, expcnt=max
#else
    asm volatile("s_waitcnt lgkmcnt(0)" ::: "memory");
#endif
    __builtin_amdgcn_s_barrier();
}

// xp layout (f16): half index = (((dirbg*512 + t)*8 + w)*64 + lane)*16,
// 16 halfs per (t,w,lane) in D-order [T*4+r]. Transposed MFMA convention:
// lane (lq,lm) holds gates T*128 + w*16 + lq*4 + r for chain bg*16+lm.
__device__ __forceinline__ size_t xp_off(int dirbg, int t, int w, int lane) {
    return (((size_t)dirbg * 512 + t) * 8 + w) * 1024 + (size_t)lane * 16;
}

// ---- kernel 1: barrier-free gather xp GEMM (transposed: A=Wih m=gate,
// B=emb-rows n=chain). Grid (dirbg=16, tchunk=32), 16 t each, fully parallel:
// e-frags gathered per lane straight from f32 emb (B n-index = lm = chain),
// converted via cvt_pkrtz; no per-iter barrier, no LDS staging of A.
__global__ __attribute__((amdgpu_flat_work_group_size(512, 512), amdgpu_waves_per_eu(2, 2)))
void xp_gemm_kernel(
    const int* __restrict__ x, const float* __restrict__ emb,
    const float* __restrict__ Wih_f, const float* __restrict__ bih_f, const float* __restrict__ bhh_f,
    const float* __restrict__ Wih_b, const float* __restrict__ bih_b, const float* __restrict__ bhh_b,
    _Float16* __restrict__ xp)
{
    const int wg  = blockIdx.x;        // dirbg
    const int dir = wg >> 3, bg = wg & 7;
    const int tb  = blockIdx.y * 16;   // t-base

    const float* Wih = dir ? Wih_b : Wih_f;
    const float* bih = dir ? bih_b : bih_f;
    const float* bhh = dir ? bhh_b : bhh_f;

    const int tid = threadIdx.x;
    const int w = tid >> 6, lane = tid & 63, lq = lane >> 4, lm = lane & 15;

    __shared__ int id_sm[16 * 16];     // [chain][t]
    if (tid < 256) {
        int i = tid >> 4, j = tid & 15;
        id_sm[i * 16 + j] = x[(size_t)(bg * 16 + i) * TT + tb + j];
    }

    // A-frags: m = gate = T*128 + w*16 + lm, k = kk*32 + lq*8 + j
    half8_t awih[4][4];
    #pragma unroll
    for (int T = 0; T < 4; ++T) {
        #pragma unroll
        for (int kk = 0; kk < 4; ++kk) {
            const float4* s = (const float4*)(Wih + (size_t)(T * 128 + w * 16 + lm) * 128 + kk * 32 + lq * 8);
            float4 v0 = s[0], v1 = s[1];
            half8_t h;
            half2_t a = pkrtz(v0.x, v0.y), b = pkrtz(v0.z, v0.w);
            half2_t c = pkrtz(v1.x, v1.y), d = pkrtz(v1.z, v1.w);
            h[0]=a[0]; h[1]=a[1]; h[2]=b[0]; h[3]=b[1];
            h[4]=c[0]; h[5]=c[1]; h[6]=d[0]; h[7]=d[1];
            awih[T][kk] = h;
        }
    }
    // bias as C-input, D-row = lq*4+r
    float4_t biasv[4];
    #pragma unroll
    for (int T = 0; T < 4; ++T) {
        int g = T * 128 + w * 16 + lq * 4;
        float4 b1 = *(const float4*)(bih + g);
        float4 b2 = *(const float4*)(bhh + g);
        biasv[T] = (float4_t){b1.x + b2.x, b1.y + b2.y, b1.z + b2.z, b1.w + b2.w};
    }
    __syncthreads();

    // e-frag double buffer; gather 8 float4 per t (row id, cols kk*32+lq*8..+8)
    half8_t EF[2][4];
    {
        int id = id_sm[lm * 16 + 0];
        const float* base = emb + (size_t)id * 128 + lq * 8;
        #pragma unroll
        for (int kk = 0; kk < 4; ++kk) {
            float4 v0 = *(const float4*)(base + kk * 32);
            float4 v1 = *(const float4*)(base + kk * 32 + 4);
            half8_t h;
            half2_t a = pkrtz(v0.x, v0.y), b = pkrtz(v0.z, v0.w);
            half2_t c = pkrtz(v1.x, v1.y), d = pkrtz(v1.z, v1.w);
            h[0]=a[0]; h[1]=a[1]; h[2]=b[0]; h[3]=b[1];
            h[4]=c[0]; h[5]=c[1]; h[6]=d[0]; h[7]=d[1];
            EF[0][kk] = h;
        }
    }

    #pragma unroll
    for (int i = 0; i < 16; ++i) {
        const int cur = i & 1;
        // issue gathers for t = i+1 (raw f32, converted after MFMA)
        float4 rv[8];
        if (i + 1 < 16) {
            int id = id_sm[lm * 16 + i + 1];
            const float* base = emb + (size_t)id * 128 + lq * 8;
            #pragma unroll
            for (int kk = 0; kk < 4; ++kk) {
                rv[2 * kk]     = *(const float4*)(base + kk * 32);
                rv[2 * kk + 1] = *(const float4*)(base + kk * 32 + 4);
            }
        }

        float4_t acc[4];
        #pragma unroll
        for (int T = 0; T < 4; ++T) acc[T] = biasv[T];
        #pragma unroll
        for (int kk = 0; kk < 4; ++kk)
            #pragma unroll
            for (int T = 0; T < 4; ++T)
                acc[T] = __builtin_amdgcn_mfma_f32_16x16x32_f16(awih[T][kk], EF[cur][kk], acc[T], 0, 0, 0);

        // pack D-order halfs [T*4+r], store 32B per lane
        half8_t p0, p1;
        {
            half2_t a = pkrtz(acc[0][0], acc[0][1]), b = pkrtz(acc[0][2], acc[0][3]);
            half2_t c = pkrtz(acc[1][0], acc[1][1]), d = pkrtz(acc[1][2], acc[1][3]);
            p0[0]=a[0]; p0[1]=a[1]; p0[2]=b[0]; p0[3]=b[1];
            p0[4]=c[0]; p0[5]=c[1]; p0[6]=d[0]; p0[7]=d[1];
        }
        {
            half2_t a = pkrtz(acc[2][0], acc[2][1]), b = pkrtz(acc[2][2], acc[2][3]);
            half2_t c = pkrtz(acc[3][0], acc[3][1]), d = pkrtz(acc[3][2], acc[3][3]);
            p1[0]=a[0]; p1[1]=a[1]; p1[2]=b[0]; p1[3]=b[1];
            p1[4]=c[0]; p1[5]=c[1]; p1[6]=d[0]; p1[7]=d[1];
        }
        half8_t* dst = (half8_t*)(xp + xp_off(wg, tb + i, w, lane));
        dst[0] = p0; dst[1] = p1;

        if (i + 1 < 16) {
            #pragma unroll
            for (int kk = 0; kk < 4; ++kk) {
                half2_t a = pkrtz(rv[2*kk].x, rv[2*kk].y), b = pkrtz(rv[2*kk].z, rv[2*kk].w);
                half2_t c = pkrtz(rv[2*kk+1].x, rv[2*kk+1].y), d = pkrtz(rv[2*kk+1].z, rv[2*kk+1].w);
                half8_t h;
                h[0]=a[0]; h[1]=a[1]; h[2]=b[0]; h[3]=b[1];
                h[4]=c[0]; h[5]=c[1]; h[6]=d[0]; h[7]=d[1];
                EF[1 - cur][kk] = h;
            }
        }
    }
}

// ---- kernel 2: recurrence, transposed MFMA (A=Whh m=gate, B=h n=chain).
// 16 WGs = (dir,bg), 16 chains each, 8 waves. Lane (lq,lm) of wave w owns
// (chain=lm, hdim=w*16+lq*4+r) for ALL 4 gate types. Packed-f16 polynomial
// activations (no exp/rcp), packed c/h/hmax state, one ds_write_b64 and one
// lgkm-only barrier per step; xp streamed with depth-2 rotating prefetch.
__global__ __attribute__((amdgpu_flat_work_group_size(512, 512), amdgpu_waves_per_eu(2, 2)))
void bilstm_rec_kernel(
    const _Float16* __restrict__ xp,
    const float* __restrict__ Whh_f, const float* __restrict__ Whh_b,
    float* __restrict__ pooled)
{
    const int wg  = blockIdx.x;        // 0..15 dirbg
    const int dir = wg >> 3, bg = wg & 7;
    const float* Whh = dir ? Whh_b : Whh_f;

    const int tid = threadIdx.x;
    const int w = tid >> 6, lane = tid & 63, lq = lane >> 4, lm = lane & 15;

    __shared__ _Float16 hsm[2][16 * 136];   // [buf][chain][hdim], +8 halfs pad

    // A-frags: Whh rows (m = gate), 64 VGPRs
    half8_t awhh[4][4];
    #pragma unroll
    for (int T = 0; T < 4; ++T) {
        #pragma unroll
        for (int kk = 0; kk < 4; ++kk) {
            const float4* s = (const float4*)(Whh + (size_t)(T * 128 + w * 16 + lm) * 128 + kk * 32 + lq * 8);
            float4 v0 = s[0], v1 = s[1];
            half8_t h;
            half2_t a = pkrtz(v0.x, v0.y), b = pkrtz(v0.z, v0.w);
            half2_t c = pkrtz(v1.x, v1.y), d = pkrtz(v1.z, v1.w);
            h[0]=a[0]; h[1]=a[1]; h[2]=b[0]; h[3]=b[1];
            h[4]=c[0]; h[5]=c[1]; h[6]=d[0]; h[7]=d[1];
            awhh[T][kk] = h;
        }
    }

    for (int k = tid; k < 2 * 16 * 136; k += 512)
        ((_Float16*)hsm)[k] = (_Float16)0.0f;

    const _Float16* xp_wl = xp + ((size_t)wg * 512 * 8 + w) * 1024 + (size_t)lane * 16;

    // rotating 4-deep prefetch buffers, lead 2
    half8_t Qa[4], Qb[4];
    {
        int ta = dir ? (TT - 1) : 0;
        const half8_t* p = (const half8_t*)(xp_wl + (size_t)ta * 8192);
        Qa[0] = p[0]; Qb[0] = p[1];
    }
    {
        int ta = dir ? (TT - 2) : 1;
        const half8_t* p = (const half8_t*)(xp_wl + (size_t)ta * 8192);
        Qa[1] = p[0]; Qb[1] = p[1];
    }
    __syncthreads();

    half2_t c01 = h2(0.0f), c23 = h2(0.0f);
    half2_t hm01 = h2(-60000.0f), hm23 = h2(-60000.0f);

    for (int tbs = 0; tbs < TT; tbs += 4) {
        #pragma unroll
        for (int P = 0; P < 4; ++P) {
            const int t = tbs + P;
            {   // prefetch xp(t+2) into buffer (P+2)&3
                int tl = (t + 2 < TT) ? (t + 2) : (TT - 1);
                int ta = dir ? (TT - 1 - tl) : tl;
                const half8_t* pp = (const half8_t*)(xp_wl + (size_t)ta * 8192);
                Qa[(P + 2) & 3] = pp[0]; Qb[(P + 2) & 3] = pp[1];
            }

            // h B-frags (n = chain = lm)
            half8_t bh[4];
            #pragma unroll
            for (int kk = 0; kk < 4; ++kk)
                bh[kk] = *(const half8_t*)&hsm[P & 1][lm * 136 + kk * 32 + lq * 8];

            // acc init from xp (bias pre-folded): D-order [T*4+r]
            float4_t acc[4];
            acc[0] = (float4_t){(float)Qa[P][0], (float)Qa[P][1], (float)Qa[P][2], (float)Qa[P][3]};
            acc[1] = (float4_t){(float)Qa[P][4], (float)Qa[P][5], (float)Qa[P][6], (float)Qa[P][7]};
            acc[2] = (float4_t){(float)Qb[P][0], (float)Qb[P][1], (float)Qb[P][2], (float)Qb[P][3]};
            acc[3] = (float4_t){(float)Qb[P][4], (float)Qb[P][5], (float)Qb[P][6], (float)Qb[P][7]};
            #pragma unroll
            for (int kk = 0; kk < 4; ++kk)
                #pragma unroll
                for (int T = 0; T < 4; ++T)
                    acc[T] = __builtin_amdgcn_mfma_f32_16x16x32_f16(awhh[T][kk], bh[kk], acc[T], 0, 0, 0);

            // packed-f16 gate math: pairs over r (hdim = w*16+lq*4 + {0,1|2,3})
            half2_t i01 = sigma_pk(pkrtz(acc[0][0], acc[0][1]));
            half2_t i23 = sigma_pk(pkrtz(acc[0][2], acc[0][3]));
            half2_t f01 = sigma_pk(pkrtz(acc[1][0], acc[1][1]));
            half2_t f23 = sigma_pk(pkrtz(acc[1][2], acc[1][3]));
            half2_t g01 = tanh_pk(pkrtz(acc[2][0], acc[2][1]));
            half2_t g23 = tanh_pk(pkrtz(acc[2][2], acc[2][3]));
            half2_t o01 = sigma_pk(pkrtz(acc[3][0], acc[3][1]));
            half2_t o23 = sigma_pk(pkrtz(acc[3][2], acc[3][3]));

            c01 = f01 * c01 + i01 * g01;
            c23 = f23 * c23 + i23 * g23;
            half2_t h01 = o01 * tanh_pk(c01);
            half2_t h23 = o23 * tanh_pk(c23);
            hm01 = __builtin_elementwise_max(hm01, h01);
            hm23 = __builtin_elementwise_max(hm23, h23);

            half4_t hv4;
            hv4[0] = h01[0]; hv4[1] = h01[1]; hv4[2] = h23[0]; hv4[3] = h23[1];
            *(half4_t*)&hsm[1 - (P & 1)][lm * 136 + w * 16 + lq * 4] = hv4;

            wg_barrier_lds();
        }
    }

    float4 o;
    o.x = (float)hm01[0]; o.y = (float)hm01[1];
    o.z = (float)hm23[0]; o.w = (float)hm23[1];
    *(float4*)&pooled[(size_t)(bg * 16 + lm) * 256 + dir * HH + w * 16 + lq * 4] = o;
}

// ---- kernel 3: pooled (128,256) -> relu(W1·+b1) -> sigmoid(W2·+b2) -> (128,1)
__global__ __launch_bounds__(64) void mlp_kernel(
    const float* __restrict__ pooled, const float* __restrict__ W1,
    const float* __restrict__ b1, const float* __restrict__ W2,
    const float* __restrict__ b2, float* __restrict__ out)
{
    const int b = blockIdx.x;
    const int j = threadIdx.x;
    const float4* p = (const float4*)(pooled + (size_t)b * 256);
    const float4* wv = (const float4*)(W1 + (size_t)j * 256);
    float s = 0.0f;
    #pragma unroll
    for (int q = 0; q < 64; ++q) {
        float4 pv = p[q];
        float4 ww = wv[q];
        s += pv.x * ww.x + pv.y * ww.y + pv.z * ww.z + pv.w * ww.w;
    }
    s += b1[j];
    s = fmaxf(s, 0.0f);
    float v = W2[j] * s;
    #pragma unroll
    for (int off = 32; off; off >>= 1) v += __shfl_down(v, off);
    if (j == 0) out[b] = 1.0f / (1.0f + __expf(-(v + b2[0])));
}

extern "C" void kernel_launch(void* const* d_in, const int* in_sizes, int n_in,
                              void* d_out, int out_size, void* d_ws, size_t ws_size,
                              hipStream_t stream) {
    const int*   x     = (const int*)d_in[0];
    const float* emb   = (const float*)d_in[1];
    const float* Wih_f = (const float*)d_in[2];
    const float* Whh_f = (const float*)d_in[3];
    const float* bih_f = (const float*)d_in[4];
    const float* bhh_f = (const float*)d_in[5];
    const float* Wih_b = (const float*)d_in[6];
    const float* Whh_b = (const float*)d_in[7];
    const float* bih_b = (const float*)d_in[8];
    const float* bhh_b = (const float*)d_in[9];
    const float* W1    = (const float*)d_in[10];
    const float* b1    = (const float*)d_in[11];
    const float* W2    = (const float*)d_in[12];
    const float* b2    = (const float*)d_in[13];
    float* out = (float*)d_out;

    char* ws = (char*)d_ws;
    float*    pooled = (float*)ws;                 // 128 KB
    _Float16* xp     = (_Float16*)(ws + 131072);   // 134.2 MB

    hipLaunchKernelGGL(xp_gemm_kernel, dim3(16, 32), dim3(512), 0, stream,
                       x, emb, Wih_f, bih_f, bhh_f, Wih_b, bih_b, bhh_b, xp);
    hipLaunchKernelGGL(bilstm_rec_kernel, dim3(16), dim3(512), 0, stream,
                       xp, Whh_f, Whh_b, pooled);
    hipLaunchKernelGGL(mlp_kernel, dim3(128), dim3(64), 0, stream,
                       pooled, W1, b1, W2, b2, out);
}

// Round 11
// 491.200 us; speedup vs baseline: 1.6155x; 1.0870x over previous
//
#include <hip/hip_runtime.h>
#include <hip/hip_fp16.h>

#define TT 512
#define HH 128

typedef _Float16 half2_t __attribute__((ext_vector_type(2)));
typedef _Float16 half4_t __attribute__((ext_vector_type(4)));
typedef _Float16 half8_t __attribute__((ext_vector_type(8)));
typedef float    float4_t __attribute__((ext_vector_type(4)));

__device__ __forceinline__ half2_t h2(float v) {
    half2_t r; r[0] = (_Float16)v; r[1] = (_Float16)v; return r;
}
__device__ __forceinline__ half2_t pkrtz(float a, float b) {
    return __builtin_bit_cast(half2_t, __builtin_amdgcn_cvt_pkrtz(a, b));
}

// ---- packed-f16 polynomial activations (no transcendentals) ----
#define TC1 0.994940f
#define TC3 -0.290799f
#define TC5 0.065507f
#define TC7 -0.0062464f
#define SC1 0.2487350f
#define SC3 -0.0181749f
#define SC5 0.00102355f
#define SC7 -0.0000244141f

__device__ __forceinline__ half2_t tanh_pk(half2_t x) {
    half2_t m = __builtin_elementwise_min(__builtin_elementwise_max(x, h2(-2.0f)), h2(2.0f));
    half2_t t = m * m;
    half2_t p = h2(TC7) * t + h2(TC5);
    p = p * t + h2(TC3);
    p = p * t + h2(TC1);
    return m * p;
}
__device__ __forceinline__ half2_t sigma_pk(half2_t x) {
    half2_t m = __builtin_elementwise_min(__builtin_elementwise_max(x, h2(-4.0f)), h2(4.0f));
    half2_t t = m * m;
    half2_t p = h2(SC7) * t + h2(SC5);
    p = p * t + h2(SC3);
    p = p * t + h2(SC1);
    return m * p + h2(0.5f);
}

// LDS-only barrier: waits lgkmcnt(0), leaves global loads/stores in flight.
__device__ __forceinline__ void wg_barrier_lds() {
#if __has_builtin(__builtin_amdgcn_s_waitcnt)
    __builtin_amdgcn_s_waitcnt(0xC07F);   // lgkmcnt(0), vmcnt=max, expcnt=max
#else
    asm volatile("s_waitcnt lgkmcnt(0)" ::: "memory");
#endif
    __builtin_amdgcn_s_barrier();
}

// xp layout (f16): half index = (((dirbg*512 + t)*8 + w)*64 + lane)*16,
// 16 halfs per (t,w,lane) in D-order [T*4+r]. Transposed MFMA convention:
// lane (lq,lm) holds gates T*128 + w*16 + lq*4 + r for chain bg*16+lm.
__device__ __forceinline__ size_t xp_off(int dirbg, int t, int w, int lane) {
    return (((size_t)dirbg * 512 + t) * 8 + w) * 1024 + (size_t)lane * 16;
}

// ---- kernel 1: block-staged xp GEMM (transposed: A=Wih m=gate, B=emb n=chain).
// Grid (dirbg=16, tchunk=32), 16 t per WG. Stage ALL 256 (chain,t) emb rows
// f32->f16 into LDS in one pipelined burst (16 float4/thread, ONE latency
// exposure), one barrier, then 16 barrier-free MFMA iterations (LDS reads
// only). Replaces the r10 gather GEMM whose per-iteration scattered gathers
// were latency-exposed 16x (~190us total).
__global__ __attribute__((amdgpu_flat_work_group_size(512, 512), amdgpu_waves_per_eu(2, 2)))
void xp_gemm_kernel(
    const int* __restrict__ x, const float* __restrict__ emb,
    const float* __restrict__ Wih_f, const float* __restrict__ bih_f, const float* __restrict__ bhh_f,
    const float* __restrict__ Wih_b, const float* __restrict__ bih_b, const float* __restrict__ bhh_b,
    _Float16* __restrict__ xp)
{
    const int wg  = blockIdx.x;        // dirbg
    const int dir = wg >> 3, bg = wg & 7;
    const int tb  = blockIdx.y * 16;   // t-base

    const float* Wih = dir ? Wih_b : Wih_f;
    const float* bih = dir ? bih_b : bih_f;
    const float* bhh = dir ? bhh_b : bhh_f;

    const int tid = threadIdx.x;
    const int w = tid >> 6, lane = tid & 63, lq = lane >> 4, lm = lane & 15;

    __shared__ int id_sm[256];                 // [chain][t]
    __shared__ _Float16 Esm[256 * 136];        // [t*16+chain][col], +8 pad

    // token ids for this (chain-group, t-chunk)
    if (tid < 256) {
        id_sm[tid] = x[(size_t)(bg * 16 + (tid >> 4)) * TT + tb + (tid & 15)];
    }

    // A-frags: m = gate = T*128 + w*16 + lm, k = kk*32 + lq*8 + j
    half8_t awih[4][4];
    #pragma unroll
    for (int T = 0; T < 4; ++T) {
        #pragma unroll
        for (int kk = 0; kk < 4; ++kk) {
            const float4* s = (const float4*)(Wih + (size_t)(T * 128 + w * 16 + lm) * 128 + kk * 32 + lq * 8);
            float4 v0 = s[0], v1 = s[1];
            half8_t h;
            half2_t a = pkrtz(v0.x, v0.y), b = pkrtz(v0.z, v0.w);
            half2_t c = pkrtz(v1.x, v1.y), d = pkrtz(v1.z, v1.w);
            h[0]=a[0]; h[1]=a[1]; h[2]=b[0]; h[3]=b[1];
            h[4]=c[0]; h[5]=c[1]; h[6]=d[0]; h[7]=d[1];
            awih[T][kk] = h;
        }
    }
    // bias as C-input, D-row = lq*4+r
    float4_t biasv[4];
    #pragma unroll
    for (int T = 0; T < 4; ++T) {
        int g = T * 128 + w * 16 + lq * 4;
        float4 b1 = *(const float4*)(bih + g);
        float4 b2 = *(const float4*)(bhh + g);
        biasv[T] = (float4_t){b1.x + b2.x, b1.y + b2.y, b1.z + b2.z, b1.w + b2.w};
    }
    __syncthreads();   // id_sm ready

    // ---- stage phase: 2 threads per (chain,t) row, 16 float4 loads each ----
    {
        const int r  = tid >> 1;            // 0..255 = chain*16 + t
        const int hf = tid & 1;             // which 64-col half
        const int chain = r >> 4, tt = r & 15;
        const float* src = emb + (size_t)id_sm[r] * 128 + hf * 64;
        float4 v[16];
        #pragma unroll
        for (int j = 0; j < 16; ++j) v[j] = *(const float4*)(src + 4 * j);
        _Float16* dst = &Esm[(tt * 16 + chain) * 136 + hf * 64];
        #pragma unroll
        for (int j = 0; j < 16; ++j) {
            half2_t a = pkrtz(v[j].x, v[j].y), b = pkrtz(v[j].z, v[j].w);
            half4_t q; q[0]=a[0]; q[1]=a[1]; q[2]=b[0]; q[3]=b[1];
            *(half4_t*)(dst + 4 * j) = q;
        }
    }
    __syncthreads();   // Esm ready; LDS is read-only below -> no more barriers

    // ---- compute phase: 16 independent t iterations, MFMA-dense ----
    #pragma unroll 4
    for (int i = 0; i < 16; ++i) {
        half8_t bfr[4];
        #pragma unroll
        for (int kk = 0; kk < 4; ++kk)
            bfr[kk] = *(const half8_t*)&Esm[(i * 16 + lm) * 136 + kk * 32 + lq * 8];

        float4_t acc[4];
        #pragma unroll
        for (int T = 0; T < 4; ++T) acc[T] = biasv[T];
        #pragma unroll
        for (int kk = 0; kk < 4; ++kk)
            #pragma unroll
            for (int T = 0; T < 4; ++T)
                acc[T] = __builtin_amdgcn_mfma_f32_16x16x32_f16(awih[T][kk], bfr[kk], acc[T], 0, 0, 0);

        half8_t p0, p1;
        {
            half2_t a = pkrtz(acc[0][0], acc[0][1]), b = pkrtz(acc[0][2], acc[0][3]);
            half2_t c = pkrtz(acc[1][0], acc[1][1]), d = pkrtz(acc[1][2], acc[1][3]);
            p0[0]=a[0]; p0[1]=a[1]; p0[2]=b[0]; p0[3]=b[1];
            p0[4]=c[0]; p0[5]=c[1]; p0[6]=d[0]; p0[7]=d[1];
        }
        {
            half2_t a = pkrtz(acc[2][0], acc[2][1]), b = pkrtz(acc[2][2], acc[2][3]);
            half2_t c = pkrtz(acc[3][0], acc[3][1]), d = pkrtz(acc[3][2], acc[3][3]);
            p1[0]=a[0]; p1[1]=a[1]; p1[2]=b[0]; p1[3]=b[1];
            p1[4]=c[0]; p1[5]=c[1]; p1[6]=d[0]; p1[7]=d[1];
        }
        half8_t* dst = (half8_t*)(xp + xp_off(wg, tb + i, w, lane));
        dst[0] = p0; dst[1] = p1;
    }
}

// ---- kernel 2: recurrence, transposed MFMA (A=Whh m=gate, B=h n=chain).
// UNCHANGED from r10 (334us, absmax 0.0): 16 WGs, packed-f16 poly acts,
// one ds_write_b64 + one lgkm-only barrier per step, depth-2 xp prefetch.
__global__ __attribute__((amdgpu_flat_work_group_size(512, 512), amdgpu_waves_per_eu(2, 2)))
void bilstm_rec_kernel(
    const _Float16* __restrict__ xp,
    const float* __restrict__ Whh_f, const float* __restrict__ Whh_b,
    float* __restrict__ pooled)
{
    const int wg  = blockIdx.x;        // 0..15 dirbg
    const int dir = wg >> 3, bg = wg & 7;
    const float* Whh = dir ? Whh_b : Whh_f;

    const int tid = threadIdx.x;
    const int w = tid >> 6, lane = tid & 63, lq = lane >> 4, lm = lane & 15;

    __shared__ _Float16 hsm[2][16 * 136];   // [buf][chain][hdim], +8 halfs pad

    half8_t awhh[4][4];
    #pragma unroll
    for (int T = 0; T < 4; ++T) {
        #pragma unroll
        for (int kk = 0; kk < 4; ++kk) {
            const float4* s = (const float4*)(Whh + (size_t)(T * 128 + w * 16 + lm) * 128 + kk * 32 + lq * 8);
            float4 v0 = s[0], v1 = s[1];
            half8_t h;
            half2_t a = pkrtz(v0.x, v0.y), b = pkrtz(v0.z, v0.w);
            half2_t c = pkrtz(v1.x, v1.y), d = pkrtz(v1.z, v1.w);
            h[0]=a[0]; h[1]=a[1]; h[2]=b[0]; h[3]=b[1];
            h[4]=c[0]; h[5]=c[1]; h[6]=d[0]; h[7]=d[1];
            awhh[T][kk] = h;
        }
    }

    for (int k = tid; k < 2 * 16 * 136; k += 512)
        ((_Float16*)hsm)[k] = (_Float16)0.0f;

    const _Float16* xp_wl = xp + ((size_t)wg * 512 * 8 + w) * 1024 + (size_t)lane * 16;

    half8_t Qa[4], Qb[4];
    {
        int ta = dir ? (TT - 1) : 0;
        const half8_t* p = (const half8_t*)(xp_wl + (size_t)ta * 8192);
        Qa[0] = p[0]; Qb[0] = p[1];
    }
    {
        int ta = dir ? (TT - 2) : 1;
        const half8_t* p = (const half8_t*)(xp_wl + (size_t)ta * 8192);
        Qa[1] = p[0]; Qb[1] = p[1];
    }
    __syncthreads();

    half2_t c01 = h2(0.0f), c23 = h2(0.0f);
    half2_t hm01 = h2(-60000.0f), hm23 = h2(-60000.0f);

    for (int tbs = 0; tbs < TT; tbs += 4) {
        #pragma unroll
        for (int P = 0; P < 4; ++P) {
            const int t = tbs + P;
            {   // prefetch xp(t+2) into buffer (P+2)&3
                int tl = (t + 2 < TT) ? (t + 2) : (TT - 1);
                int ta = dir ? (TT - 1 - tl) : tl;
                const half8_t* pp = (const half8_t*)(xp_wl + (size_t)ta * 8192);
                Qa[(P + 2) & 3] = pp[0]; Qb[(P + 2) & 3] = pp[1];
            }

            half8_t bh[4];
            #pragma unroll
            for (int kk = 0; kk < 4; ++kk)
                bh[kk] = *(const half8_t*)&hsm[P & 1][lm * 136 + kk * 32 + lq * 8];

            float4_t acc[4];
            acc[0] = (float4_t){(float)Qa[P][0], (float)Qa[P][1], (float)Qa[P][2], (float)Qa[P][3]};
            acc[1] = (float4_t){(float)Qa[P][4], (float)Qa[P][5], (float)Qa[P][6], (float)Qa[P][7]};
            acc[2] = (float4_t){(float)Qb[P][0], (float)Qb[P][1], (float)Qb[P][2], (float)Qb[P][3]};
            acc[3] = (float4_t){(float)Qb[P][4], (float)Qb[P][5], (float)Qb[P][6], (float)Qb[P][7]};
            #pragma unroll
            for (int kk = 0; kk < 4; ++kk)
                #pragma unroll
                for (int T = 0; T < 4; ++T)
                    acc[T] = __builtin_amdgcn_mfma_f32_16x16x32_f16(awhh[T][kk], bh[kk], acc[T], 0, 0, 0);

            half2_t i01 = sigma_pk(pkrtz(acc[0][0], acc[0][1]));
            half2_t i23 = sigma_pk(pkrtz(acc[0][2], acc[0][3]));
            half2_t f01 = sigma_pk(pkrtz(acc[1][0], acc[1][1]));
            half2_t f23 = sigma_pk(pkrtz(acc[1][2], acc[1][3]));
            half2_t g01 = tanh_pk(pkrtz(acc[2][0], acc[2][1]));
            half2_t g23 = tanh_pk(pkrtz(acc[2][2], acc[2][3]));
            half2_t o01 = sigma_pk(pkrtz(acc[3][0], acc[3][1]));
            half2_t o23 = sigma_pk(pkrtz(acc[3][2], acc[3][3]));

            c01 = f01 * c01 + i01 * g01;
            c23 = f23 * c23 + i23 * g23;
            half2_t h01 = o01 * tanh_pk(c01);
            half2_t h23 = o23 * tanh_pk(c23);
            hm01 = __builtin_elementwise_max(hm01, h01);
            hm23 = __builtin_elementwise_max(hm23, h23);

            half4_t hv4;
            hv4[0] = h01[0]; hv4[1] = h01[1]; hv4[2] = h23[0]; hv4[3] = h23[1];
            *(half4_t*)&hsm[1 - (P & 1)][lm * 136 + w * 16 + lq * 4] = hv4;

            wg_barrier_lds();
        }
    }

    float4 o;
    o.x = (float)hm01[0]; o.y = (float)hm01[1];
    o.z = (float)hm23[0]; o.w = (float)hm23[1];
    *(float4*)&pooled[(size_t)(bg * 16 + lm) * 256 + dir * HH + w * 16 + lq * 4] = o;
}

// ---- kernel 3: pooled (128,256) -> relu(W1·+b1) -> sigmoid(W2·+b2) -> (128,1)
__global__ __launch_bounds__(64) void mlp_kernel(
    const float* __restrict__ pooled, const float* __restrict__ W1,
    const float* __restrict__ b1, const float* __restrict__ W2,
    const float* __restrict__ b2, float* __restrict__ out)
{
    const int b = blockIdx.x;
    const int j = threadIdx.x;
    const float4* p = (const float4*)(pooled + (size_t)b * 256);
    const float4* wv = (const float4*)(W1 + (size_t)j * 256);
    float s = 0.0f;
    #pragma unroll
    for (int q = 0; q < 64; ++q) {
        float4 pv = p[q];
        float4 ww = wv[q];
        s += pv.x * ww.x + pv.y * ww.y + pv.z * ww.z + pv.w * ww.w;
    }
    s += b1[j];
    s = fmaxf(s, 0.0f);
    float v = W2[j] * s;
    #pragma unroll
    for (int off = 32; off; off >>= 1) v += __shfl_down(v, off);
    if (j == 0) out[b] = 1.0f / (1.0f + __expf(-(v + b2[0])));
}

extern "C" void kernel_launch(void* const* d_in, const int* in_sizes, int n_in,
                              void* d_out, int out_size, void* d_ws, size_t ws_size,
                              hipStream_t stream) {
    const int*   x     = (const int*)d_in[0];
    const float* emb   = (const float*)d_in[1];
    const float* Wih_f = (const float*)d_in[2];
    const float* Whh_f = (const float*)d_in[3];
    const float* bih_f = (const float*)d_in[4];
    const float* bhh_f = (const float*)d_in[5];
    const float* Wih_b = (const float*)d_in[6];
    const float* Whh_b = (const float*)d_in[7];
    const float* bih_b = (const float*)d_in[8];
    const float* bhh_b = (const float*)d_in[9];
    const float* W1    = (const float*)d_in[10];
    const float* b1    = (const float*)d_in[11];
    const float* W2    = (const float*)d_in[12];
    const float* b2    = (const float*)d_in[13];
    float* out = (float*)d_out;

    char* ws = (char*)d_ws;
    float*    pooled = (float*)ws;                 // 128 KB
    _Float16* xp     = (_Float16*)(ws + 131072);   // 134.2 MB

    hipLaunchKernelGGL(xp_gemm_kernel, dim3(16, 32), dim3(512), 0, stream,
                       x, emb, Wih_f, bih_f, bhh_f, Wih_b, bih_b, bhh_b, xp);
    hipLaunchKernelGGL(bilstm_rec_kernel, dim3(16), dim3(512), 0, stream,
                       xp, Whh_f, Whh_b, pooled);
    hipLaunchKernelGGL(mlp_kernel, dim3(128), dim3(64), 0, stream,
                       pooled, W1, b1, W2, b2, out);
}